// Round 6
// baseline (513.578 us; speedup 1.0000x reference)
//
#include <hip/hip_runtime.h>

// out = (sum_k h[k] * S_k) @ x  — COO SpMM, bucket-binned, atomic-free accumulate.
//
// Round-5 lesson: spmv ran at 21.5 cy/edge vs ~4-5 cy/edge TA floor ->
// instruction-issue bound (2 VMEM + 2 DS + ~6 VALU per edge). Fix: float2
// pair-processing — 32 lanes cover one 256B x-row, so each wave processes
// TWO edges per instruction: half-wave 0 walks the bucket's class-0 (even
// row) stream, half-wave 1 the class-1 (odd row) stream. Parity pairing =>
// intra-instruction LDS rows always distinct (no collision logic). The two
// waves split each class positionally and use PRIVATE acc copies (2x16KB,
// merged at the end) so cross-wave hazards are impossible.
//
// Binning (count/scan/scatter, NSTREAM=3126, GWG=128) unchanged from round 5.
//
// ws: cnt[NSTREAM*G] | ssBeg[NSTREAM+1] | pad | payload[KE] (int2)  (~65.6MB)

#define RPB   64           // rows per bucket
#define SUB   2            // row classes
#define GWG   128          // count/scatter workgroups

static __global__ __launch_bounds__(1024) void count_kernel(
    const int* __restrict__ rows, int* __restrict__ cnt,
    int KE, int NSTREAM, int chunk)
{
    extern __shared__ int hist[];              // NSTREAM ints
    const int g = blockIdx.x;
    for (int j = threadIdx.x; j < NSTREAM; j += blockDim.x) hist[j] = 0;
    __syncthreads();
    const int lo = g * chunk;
    const int hi = min(lo + chunk, KE);
    for (int e = lo + threadIdx.x; e < hi; e += blockDim.x) {
        const int r = rows[e];
        atomicAdd(&hist[((r >> 6) << 1) | (r & 1)], 1);
    }
    __syncthreads();
    for (int j = threadIdx.x; j < NSTREAM; j += blockDim.x)
        cnt[(size_t)j * GWG + g] = hist[j];
}

// B1: per-stream exclusive scan of its GWG counts (in place); total -> ssBeg[s]
static __global__ __launch_bounds__(GWG) void scan1_kernel(
    int* __restrict__ cnt, int* __restrict__ ssBeg)
{
    __shared__ int tmp[GWG];
    const int s = blockIdx.x;
    const int t = threadIdx.x;
    const int v = cnt[(size_t)s * GWG + t];
    tmp[t] = v;
    __syncthreads();
    for (int d = 1; d < GWG; d <<= 1) {
        int u = (t >= d) ? tmp[t - d] : 0;
        __syncthreads();
        tmp[t] += u;
        __syncthreads();
    }
    cnt[(size_t)s * GWG + t] = tmp[t] - v;     // exclusive
    if (t == GWG - 1) ssBeg[s] = tmp[t];       // stream total
}

// B2: exclusive scan of ssBeg[0..n) in place; ssBeg[n] = grand total
static __global__ __launch_bounds__(1024) void scan2_kernel(
    int* __restrict__ a, int n)
{
    __shared__ int sums[1024];
    const int t = threadIdx.x;
    const int chunk = (n + 1023) >> 10;
    const int lo = t * chunk;
    const int hi = min(lo + chunk, n);
    int s = 0;
    for (int i = lo; i < hi; ++i) s += a[i];
    sums[t] = s;
    __syncthreads();
    for (int d = 1; d < 1024; d <<= 1) {
        int v = (t >= d) ? sums[t - d] : 0;
        __syncthreads();
        sums[t] += v;
        __syncthreads();
    }
    int run = (t > 0) ? sums[t - 1] : 0;
    for (int i = lo; i < hi; ++i) {
        const int cv = a[i];
        a[i] = run;
        run += cv;
    }
    if (t == 1023) a[n] = sums[1023];
}

// B3: cnt[s][g] += stream base
static __global__ __launch_bounds__(1024) void scan3_kernel(
    int* __restrict__ cnt, const int* __restrict__ ssBeg, int total)
{
    const int i = blockIdx.x * blockDim.x + threadIdx.x;
    if (i < total) cnt[i] += ssBeg[i >> 7];    // i / GWG (GWG=128)
}

static __global__ __launch_bounds__(1024) void scatter_kernel(
    const int*   __restrict__ rows,
    const int*   __restrict__ cols,
    const float* __restrict__ vals,
    const float* __restrict__ h,
    const int*   __restrict__ cnt,
    int2*        __restrict__ payload,
    int KE, int E, int K, int NSTREAM, int chunk)
{
    extern __shared__ int lcur[];              // NSTREAM cursors
    const int g = blockIdx.x;
    for (int j = threadIdx.x; j < NSTREAM; j += blockDim.x)
        lcur[j] = cnt[(size_t)j * GWG + g];
    __syncthreads();
    const int lo = g * chunk;
    const int hi = min(lo + chunk, KE);
    if (lo >= hi) return;
    const int k0 = lo / E;
    const int k1 = min((hi - 1) / E, K - 1);
    for (int k = k0; k <= k1; ++k) {
        const float hk = h[k];
        const int s0 = max(lo, k * E);
        const int s1 = min(hi, (k + 1) * E);
        for (int e = s0 + threadIdx.x; e < s1; e += blockDim.x) {
            const int r = rows[e];
            const int st = ((r >> 6) << 1) | (r & 1);
            const int pos = atomicAdd(&lcur[st], 1);      // int LDS atomic
            payload[pos] = make_int2(((r & 63) << 17) | cols[e],
                                     __float_as_int(hk * vals[e]));
        }
    }
}

static __global__ __launch_bounds__(128) void spmv_kernel(
    const int*  __restrict__ ssBeg,
    const int2* __restrict__ payload,
    const float* __restrict__ x,
    float*       __restrict__ out,
    int N)
{
    __shared__ float2 acc[2][RPB * 32];        // wave-private copies, 16KB each
    const int tid = threadIdx.x;
    for (int i = tid; i < RPB * 32; i += 128) {
        acc[0][i] = make_float2(0.f, 0.f);
        acc[1][i] = make_float2(0.f, 0.f);
    }
    __syncthreads();

    const int b    = blockIdx.x;
    const int lane = tid & 63;
    const int wv   = tid >> 6;                 // 0..1 (acc copy owner)
    const int m    = lane & 31;                // feature-pair index
    const int hl   = lane >> 5;                // half: 0 -> class0, 1 -> class1
    const float2* xp = (const float2*)x;
    float2* ac = acc[wv];

    const int l0 = ssBeg[2 * b];
    const int r0 = ssBeg[2 * b + 1];
    const int r1 = ssBeg[2 * b + 2];
    const int n0 = r0 - l0, n1 = r1 - r0;
    const int h0 = n0 >> 1, h1 = n1 >> 1;
    // wave wv's slices of the two class streams
    const int a0 = l0 + h0 * wv, b0 = wv ? r0 : (l0 + h0);
    const int a1 = r0 + h1 * wv, b1 = wv ? r1 : (r0 + h1);
    const int len0 = b0 - a0, len1 = b1 - a1;
    const int np = min(len0, len1);
    const int base = hl ? a1 : a0;             // per-lane stream base

    int j = 0;
    while (j + 8 <= np) {                      // 8 pairs = 16 edges in flight
        int2 pp[8];
        float2 xx[8];
        #pragma unroll
        for (int q = 0; q < 8; ++q) pp[q] = payload[base + j + q];
        #pragma unroll
        for (int q = 0; q < 8; ++q)
            xx[q] = xp[(size_t)(pp[q].x & 0x1FFFF) * 32 + m];
        #pragma unroll
        for (int q = 0; q < 8; ++q) {
            const float w  = __int_as_float(pp[q].y);
            const int   rl = pp[q].x >> 17;    // even for half0, odd for half1
            float2 cur = ac[rl * 32 + m];
            cur.x += w * xx[q].x;
            cur.y += w * xx[q].y;
            ac[rl * 32 + m] = cur;
        }
        j += 8;
    }
    for (; j < np; ++j) {
        const int2 p = payload[base + j];
        const float2 xv = xp[(size_t)(p.x & 0x1FFFF) * 32 + m];
        const float w  = __int_as_float(p.y);
        const int   rl = p.x >> 17;
        float2 cur = ac[rl * 32 + m];
        cur.x += w * xv.x;
        cur.y += w * xv.y;
        ac[rl * 32 + m] = cur;
    }
    // tails (one class is longer by |len0-len1|): half-wave 0 processes solo
    for (int t = a0 + np; t < b0; ++t) {
        const int2 p = payload[t];
        const float2 xv = xp[(size_t)(p.x & 0x1FFFF) * 32 + m];
        if (hl == 0) {
            const float w  = __int_as_float(p.y);
            const int   rl = p.x >> 17;
            float2 cur = ac[rl * 32 + m];
            cur.x += w * xv.x;
            cur.y += w * xv.y;
            ac[rl * 32 + m] = cur;
        }
    }
    for (int t = a1 + np; t < b1; ++t) {
        const int2 p = payload[t];
        const float2 xv = xp[(size_t)(p.x & 0x1FFFF) * 32 + m];
        if (hl == 0) {
            const float w  = __int_as_float(p.y);
            const int   rl = p.x >> 17;
            float2 cur = ac[rl * 32 + m];
            cur.x += w * xv.x;
            cur.y += w * xv.y;
            ac[rl * 32 + m] = cur;
        }
    }
    __syncthreads();

    // merge the two copies and store
    const int basev = b * RPB;
    const int nrow = min(RPB, N - basev);
    float2* op = (float2*)(out + (size_t)basev * 64);
    for (int i = tid; i < nrow * 32; i += 128) {
        const float2 u = acc[0][i];
        const float2 v = acc[1][i];
        op[i] = make_float2(u.x + v.x, u.y + v.y);
    }
}

// Round-1 fallback (atomic scatter) if ws is too small.
static __global__ __launch_bounds__(256) void gtconv_scatter(
    const float* __restrict__ x, const float* __restrict__ h,
    const float* __restrict__ vals, const int* __restrict__ rows,
    const int* __restrict__ cols, float* __restrict__ out, int KE, int E)
{
    const int lane = threadIdx.x & 63;
    int wave = (blockIdx.x * blockDim.x + threadIdx.x) >> 6;
    const int nwaves = (gridDim.x * blockDim.x) >> 6;
    for (int e = wave; e < KE; e += nwaves) {
        float w = h[e / E] * vals[e];
        float xv = x[(size_t)cols[e] * 64 + lane];
        unsafeAtomicAdd(&out[(size_t)rows[e] * 64 + lane], xv * w);
    }
}

extern "C" void kernel_launch(void* const* d_in, const int* in_sizes, int n_in,
                              void* d_out, int out_size, void* d_ws, size_t ws_size,
                              hipStream_t stream) {
    const float* x    = (const float*)d_in[0];
    const float* h    = (const float*)d_in[1];
    const float* vals = (const float*)d_in[2];
    const int*   rows = (const int*)d_in[3];
    const int*   cols = (const int*)d_in[4];
    float* out = (float*)d_out;

    const int K  = in_sizes[1];
    const int KE = in_sizes[2];
    const int E  = KE / K;
    const int F  = 64;
    const int N  = in_sizes[0] / F;
    const int NB      = (N + RPB - 1) / RPB;       // 1563
    const int NSTREAM = NB * SUB;                  // 3126

    const size_t lds_need = (size_t)NSTREAM * 4;   // count/scatter LDS
    const size_t cnt_off  = 0;
    const size_t cnt_sz   = (size_t)NSTREAM * GWG * 4;
    const size_t ss_off   = cnt_off + cnt_sz;
    const size_t ss_sz    = (size_t)(NSTREAM + 1) * 4;
    const size_t pl_off   = (ss_off + ss_sz + 15) & ~(size_t)15;
    const size_t need     = pl_off + (size_t)KE * 8;

    if (ws_size < need || lds_need > 64 * 1024) {
        hipMemsetAsync(out, 0, (size_t)out_size * sizeof(float), stream);
        gtconv_scatter<<<8192, 256, 0, stream>>>(x, h, vals, rows, cols, out, KE, E);
        return;
    }

    char* ws = (char*)d_ws;
    int*  cnt     = (int*)(ws + cnt_off);
    int*  ssBeg   = (int*)(ws + ss_off);
    int2* payload = (int2*)(ws + pl_off);

    const int chunk = (KE + GWG - 1) / GWG;

    count_kernel<<<GWG, 1024, lds_need, stream>>>(rows, cnt, KE, NSTREAM, chunk);
    scan1_kernel<<<NSTREAM, GWG, 0, stream>>>(cnt, ssBeg);
    scan2_kernel<<<1, 1024, 0, stream>>>(ssBeg, NSTREAM);
    const int total = NSTREAM * GWG;
    scan3_kernel<<<(total + 1023) / 1024, 1024, 0, stream>>>(cnt, ssBeg, total);
    scatter_kernel<<<GWG, 1024, lds_need, stream>>>(rows, cols, vals, h, cnt,
                                                    payload, KE, E, K, NSTREAM, chunk);
    spmv_kernel<<<NB, 128, 0, stream>>>(ssBeg, payload, x, out, N);
}

// Round 7
// 415.784 us; speedup vs baseline: 1.2352x; 1.2352x over previous
//
#include <hip/hip_runtime.h>

// out = (sum_k h[k] * S_k) @ x  — COO SpMM, bucket-binned, atomic-free accumulate.
//
// Round-6 lesson: float2 pairing halved instructions but also halved
// occupancy (32KB LDS / 128 threads -> 17% occ) — spmv is LATENCY-bound,
// so waves/CU is what matters. Round 7: revert to round-5's proven
// scalar per-wave loop, but 4 waves/block: wave wv = class (wv&1) x
// positional half (wv>>1); two 16KB acc copies (copy = half), parity
// classes make rows disjoint within a copy -> race-free, merge at end.
// 1563 blocks x 4 waves, 32KB LDS -> ~20 waves/CU (vs 12 in round 5).
//
// Binning (count/scan/scatter, NSTREAM=3126, GWG=128) unchanged from round 5.
//
// ws: cnt[NSTREAM*G] | ssBeg[NSTREAM+1] | pad | payload[KE] (int2)  (~65.6MB)

#define RPB   64           // rows per bucket
#define SUB   2            // row classes
#define GWG   128          // count/scatter workgroups

static __global__ __launch_bounds__(1024) void count_kernel(
    const int* __restrict__ rows, int* __restrict__ cnt,
    int KE, int NSTREAM, int chunk)
{
    extern __shared__ int hist[];              // NSTREAM ints
    const int g = blockIdx.x;
    for (int j = threadIdx.x; j < NSTREAM; j += blockDim.x) hist[j] = 0;
    __syncthreads();
    const int lo = g * chunk;
    const int hi = min(lo + chunk, KE);
    for (int e = lo + threadIdx.x; e < hi; e += blockDim.x) {
        const int r = rows[e];
        atomicAdd(&hist[((r >> 6) << 1) | (r & 1)], 1);
    }
    __syncthreads();
    for (int j = threadIdx.x; j < NSTREAM; j += blockDim.x)
        cnt[(size_t)j * GWG + g] = hist[j];
}

// B1: per-stream exclusive scan of its GWG counts (in place); total -> ssBeg[s]
static __global__ __launch_bounds__(GWG) void scan1_kernel(
    int* __restrict__ cnt, int* __restrict__ ssBeg)
{
    __shared__ int tmp[GWG];
    const int s = blockIdx.x;
    const int t = threadIdx.x;
    const int v = cnt[(size_t)s * GWG + t];
    tmp[t] = v;
    __syncthreads();
    for (int d = 1; d < GWG; d <<= 1) {
        int u = (t >= d) ? tmp[t - d] : 0;
        __syncthreads();
        tmp[t] += u;
        __syncthreads();
    }
    cnt[(size_t)s * GWG + t] = tmp[t] - v;     // exclusive
    if (t == GWG - 1) ssBeg[s] = tmp[t];       // stream total
}

// B2: exclusive scan of ssBeg[0..n) in place; ssBeg[n] = grand total
static __global__ __launch_bounds__(1024) void scan2_kernel(
    int* __restrict__ a, int n)
{
    __shared__ int sums[1024];
    const int t = threadIdx.x;
    const int chunk = (n + 1023) >> 10;
    const int lo = t * chunk;
    const int hi = min(lo + chunk, n);
    int s = 0;
    for (int i = lo; i < hi; ++i) s += a[i];
    sums[t] = s;
    __syncthreads();
    for (int d = 1; d < 1024; d <<= 1) {
        int v = (t >= d) ? sums[t - d] : 0;
        __syncthreads();
        sums[t] += v;
        __syncthreads();
    }
    int run = (t > 0) ? sums[t - 1] : 0;
    for (int i = lo; i < hi; ++i) {
        const int cv = a[i];
        a[i] = run;
        run += cv;
    }
    if (t == 1023) a[n] = sums[1023];
}

// B3: cnt[s][g] += stream base
static __global__ __launch_bounds__(1024) void scan3_kernel(
    int* __restrict__ cnt, const int* __restrict__ ssBeg, int total)
{
    const int i = blockIdx.x * blockDim.x + threadIdx.x;
    if (i < total) cnt[i] += ssBeg[i >> 7];    // i / GWG (GWG=128)
}

static __global__ __launch_bounds__(1024) void scatter_kernel(
    const int*   __restrict__ rows,
    const int*   __restrict__ cols,
    const float* __restrict__ vals,
    const float* __restrict__ h,
    const int*   __restrict__ cnt,
    int2*        __restrict__ payload,
    int KE, int E, int K, int NSTREAM, int chunk)
{
    extern __shared__ int lcur[];              // NSTREAM cursors
    const int g = blockIdx.x;
    for (int j = threadIdx.x; j < NSTREAM; j += blockDim.x)
        lcur[j] = cnt[(size_t)j * GWG + g];
    __syncthreads();
    const int lo = g * chunk;
    const int hi = min(lo + chunk, KE);
    if (lo >= hi) return;
    const int k0 = lo / E;
    const int k1 = min((hi - 1) / E, K - 1);
    for (int k = k0; k <= k1; ++k) {
        const float hk = h[k];
        const int s0 = max(lo, k * E);
        const int s1 = min(hi, (k + 1) * E);
        for (int e = s0 + threadIdx.x; e < s1; e += blockDim.x) {
            const int r = rows[e];
            const int st = ((r >> 6) << 1) | (r & 1);
            const int pos = atomicAdd(&lcur[st], 1);      // int LDS atomic
            payload[pos] = make_int2(((r & 63) << 17) | cols[e],
                                     __float_as_int(hk * vals[e]));
        }
    }
}

static __global__ __launch_bounds__(256) void spmv_kernel(
    const int*  __restrict__ ssBeg,
    const int2* __restrict__ payload,
    const float* __restrict__ x,
    float*       __restrict__ out,
    int N)
{
    __shared__ float acc[2][RPB * 64];         // two copies, 16KB each
    const int tid = threadIdx.x;
    for (int i = tid; i < RPB * 64; i += 256) {
        acc[0][i] = 0.f;
        acc[1][i] = 0.f;
    }
    __syncthreads();

    const int b    = blockIdx.x;
    const int lane = tid & 63;
    const int wv   = tid >> 6;                 // 0..3
    const int cls  = wv & 1;                   // row parity class
    const int half = wv >> 1;                  // positional half = copy index
    float* ac = acc[half];                     // waves {0,1}->copy0, {2,3}->copy1
                                               // within a copy, classes 0/1 touch
                                               // disjoint (even/odd) rows: race-free
    const int s  = 2 * b + cls;
    const int ss = ssBeg[s];
    const int se = ssBeg[s + 1];
    const int mid = ss + ((se - ss) >> 1);
    int e        = half ? mid : ss;
    const int be = half ? se  : mid;

    // 16 edges per iteration: all 16 payload loads + 16 gathers in flight
    // before the (wave-exclusive, hazard-free) LDS read-modify-writes.
    while (e + 16 <= be) {
        int2 pa[8], pb[8];
        float xa[8], xb[8];
        #pragma unroll
        for (int j = 0; j < 8; ++j) pa[j] = payload[e + j];
        #pragma unroll
        for (int j = 0; j < 8; ++j) pb[j] = payload[e + 8 + j];
        #pragma unroll
        for (int j = 0; j < 8; ++j)
            xa[j] = x[(size_t)(pa[j].x & 0x1FFFF) * 64 + lane];
        #pragma unroll
        for (int j = 0; j < 8; ++j)
            xb[j] = x[(size_t)(pb[j].x & 0x1FFFF) * 64 + lane];
        #pragma unroll
        for (int j = 0; j < 8; ++j)
            ac[(pa[j].x >> 17) * 64 + lane] += __int_as_float(pa[j].y) * xa[j];
        #pragma unroll
        for (int j = 0; j < 8; ++j)
            ac[(pb[j].x >> 17) * 64 + lane] += __int_as_float(pb[j].y) * xb[j];
        e += 16;
    }
    for (; e < be; ++e) {
        const int2 p = payload[e];
        ac[(p.x >> 17) * 64 + lane] +=
            __int_as_float(p.y) * x[(size_t)(p.x & 0x1FFFF) * 64 + lane];
    }
    __syncthreads();

    // merge the two copies and store
    const int base = b * RPB;
    const int nrow = min(RPB, N - base);
    for (int i = tid; i < nrow * 64; i += 256)
        out[(size_t)base * 64 + i] = acc[0][i] + acc[1][i];
}

// Round-1 fallback (atomic scatter) if ws is too small.
static __global__ __launch_bounds__(256) void gtconv_scatter(
    const float* __restrict__ x, const float* __restrict__ h,
    const float* __restrict__ vals, const int* __restrict__ rows,
    const int* __restrict__ cols, float* __restrict__ out, int KE, int E)
{
    const int lane = threadIdx.x & 63;
    int wave = (blockIdx.x * blockDim.x + threadIdx.x) >> 6;
    const int nwaves = (gridDim.x * blockDim.x) >> 6;
    for (int e = wave; e < KE; e += nwaves) {
        float w = h[e / E] * vals[e];
        float xv = x[(size_t)cols[e] * 64 + lane];
        unsafeAtomicAdd(&out[(size_t)rows[e] * 64 + lane], xv * w);
    }
}

extern "C" void kernel_launch(void* const* d_in, const int* in_sizes, int n_in,
                              void* d_out, int out_size, void* d_ws, size_t ws_size,
                              hipStream_t stream) {
    const float* x    = (const float*)d_in[0];
    const float* h    = (const float*)d_in[1];
    const float* vals = (const float*)d_in[2];
    const int*   rows = (const int*)d_in[3];
    const int*   cols = (const int*)d_in[4];
    float* out = (float*)d_out;

    const int K  = in_sizes[1];
    const int KE = in_sizes[2];
    const int E  = KE / K;
    const int F  = 64;
    const int N  = in_sizes[0] / F;
    const int NB      = (N + RPB - 1) / RPB;       // 1563
    const int NSTREAM = NB * SUB;                  // 3126

    const size_t lds_need = (size_t)NSTREAM * 4;   // count/scatter LDS
    const size_t cnt_off  = 0;
    const size_t cnt_sz   = (size_t)NSTREAM * GWG * 4;
    const size_t ss_off   = cnt_off + cnt_sz;
    const size_t ss_sz    = (size_t)(NSTREAM + 1) * 4;
    const size_t pl_off   = (ss_off + ss_sz + 15) & ~(size_t)15;
    const size_t need     = pl_off + (size_t)KE * 8;

    if (ws_size < need || lds_need > 64 * 1024) {
        hipMemsetAsync(out, 0, (size_t)out_size * sizeof(float), stream);
        gtconv_scatter<<<8192, 256, 0, stream>>>(x, h, vals, rows, cols, out, KE, E);
        return;
    }

    char* ws = (char*)d_ws;
    int*  cnt     = (int*)(ws + cnt_off);
    int*  ssBeg   = (int*)(ws + ss_off);
    int2* payload = (int2*)(ws + pl_off);

    const int chunk = (KE + GWG - 1) / GWG;

    count_kernel<<<GWG, 1024, lds_need, stream>>>(rows, cnt, KE, NSTREAM, chunk);
    scan1_kernel<<<NSTREAM, GWG, 0, stream>>>(cnt, ssBeg);
    scan2_kernel<<<1, 1024, 0, stream>>>(ssBeg, NSTREAM);
    const int total = NSTREAM * GWG;
    scan3_kernel<<<(total + 1023) / 1024, 1024, 0, stream>>>(cnt, ssBeg, total);
    scatter_kernel<<<GWG, 1024, lds_need, stream>>>(rows, cols, vals, h, cnt,
                                                    payload, KE, E, K, NSTREAM, chunk);
    spmv_kernel<<<NB, 256, 0, stream>>>(ssBeg, payload, x, out, N);
}

// Round 8
// 391.240 us; speedup vs baseline: 1.3127x; 1.0627x over previous
//
#include <hip/hip_runtime.h>
#include <hip/hip_bf16.h>

// out = (sum_k h[k] * S_k) @ x  — COO SpMM, bucket-binned, atomic-free accumulate.
//
// Rounds 5-7 evidence: spmv pinned at ~21.5 cy/edge, FETCH ~877MB @ ~3.1TB/s
// regardless of wave count or instruction mix -> BANDWIDTH-bound on the
// x-gather fetch path (x=25.6MB >> 4MB/XCD L2 -> ~32x refetch from LLC).
// Round 8: halve gathered bytes — convert x to a bf16 copy in ws (12.8MB)
// and gather 2B/lane. Accumulation stays f32 in LDS. Expected: spmv fetch
// ~480MB, dur ~160us. f32-gather fallback if ws can't hold the copy.
//
// Binning (count/scan/scatter, NSTREAM=3126, GWG=128) unchanged from round 5.
// spmv: round-5 structure (128 thr, wave=parity class, single 16KB acc).
//
// ws: cnt[NSTREAM*G] | ssBeg[NSTREAM+1] | pad | payload[KE] int2 | xh[N*64] bf16

#define RPB   64           // rows per bucket
#define SUB   2            // row classes
#define GWG   128          // count/scatter workgroups

static __global__ __launch_bounds__(1024) void count_kernel(
    const int* __restrict__ rows, int* __restrict__ cnt,
    int KE, int NSTREAM, int chunk)
{
    extern __shared__ int hist[];              // NSTREAM ints
    const int g = blockIdx.x;
    for (int j = threadIdx.x; j < NSTREAM; j += blockDim.x) hist[j] = 0;
    __syncthreads();
    const int lo = g * chunk;
    const int hi = min(lo + chunk, KE);
    for (int e = lo + threadIdx.x; e < hi; e += blockDim.x) {
        const int r = rows[e];
        atomicAdd(&hist[((r >> 6) << 1) | (r & 1)], 1);
    }
    __syncthreads();
    for (int j = threadIdx.x; j < NSTREAM; j += blockDim.x)
        cnt[(size_t)j * GWG + g] = hist[j];
}

// B1: per-stream exclusive scan of its GWG counts (in place); total -> ssBeg[s]
static __global__ __launch_bounds__(GWG) void scan1_kernel(
    int* __restrict__ cnt, int* __restrict__ ssBeg)
{
    __shared__ int tmp[GWG];
    const int s = blockIdx.x;
    const int t = threadIdx.x;
    const int v = cnt[(size_t)s * GWG + t];
    tmp[t] = v;
    __syncthreads();
    for (int d = 1; d < GWG; d <<= 1) {
        int u = (t >= d) ? tmp[t - d] : 0;
        __syncthreads();
        tmp[t] += u;
        __syncthreads();
    }
    cnt[(size_t)s * GWG + t] = tmp[t] - v;     // exclusive
    if (t == GWG - 1) ssBeg[s] = tmp[t];       // stream total
}

// B2: exclusive scan of ssBeg[0..n) in place; ssBeg[n] = grand total
static __global__ __launch_bounds__(1024) void scan2_kernel(
    int* __restrict__ a, int n)
{
    __shared__ int sums[1024];
    const int t = threadIdx.x;
    const int chunk = (n + 1023) >> 10;
    const int lo = t * chunk;
    const int hi = min(lo + chunk, n);
    int s = 0;
    for (int i = lo; i < hi; ++i) s += a[i];
    sums[t] = s;
    __syncthreads();
    for (int d = 1; d < 1024; d <<= 1) {
        int v = (t >= d) ? sums[t - d] : 0;
        __syncthreads();
        sums[t] += v;
        __syncthreads();
    }
    int run = (t > 0) ? sums[t - 1] : 0;
    for (int i = lo; i < hi; ++i) {
        const int cv = a[i];
        a[i] = run;
        run += cv;
    }
    if (t == 1023) a[n] = sums[1023];
}

// B3: cnt[s][g] += stream base
static __global__ __launch_bounds__(1024) void scan3_kernel(
    int* __restrict__ cnt, const int* __restrict__ ssBeg, int total)
{
    const int i = blockIdx.x * blockDim.x + threadIdx.x;
    if (i < total) cnt[i] += ssBeg[i >> 7];    // i / GWG (GWG=128)
}

static __global__ __launch_bounds__(1024) void scatter_kernel(
    const int*   __restrict__ rows,
    const int*   __restrict__ cols,
    const float* __restrict__ vals,
    const float* __restrict__ h,
    const int*   __restrict__ cnt,
    int2*        __restrict__ payload,
    int KE, int E, int K, int NSTREAM, int chunk)
{
    extern __shared__ int lcur[];              // NSTREAM cursors
    const int g = blockIdx.x;
    for (int j = threadIdx.x; j < NSTREAM; j += blockDim.x)
        lcur[j] = cnt[(size_t)j * GWG + g];
    __syncthreads();
    const int lo = g * chunk;
    const int hi = min(lo + chunk, KE);
    if (lo >= hi) return;
    const int k0 = lo / E;
    const int k1 = min((hi - 1) / E, K - 1);
    for (int k = k0; k <= k1; ++k) {
        const float hk = h[k];
        const int s0 = max(lo, k * E);
        const int s1 = min(hi, (k + 1) * E);
        for (int e = s0 + threadIdx.x; e < s1; e += blockDim.x) {
            const int r = rows[e];
            const int st = ((r >> 6) << 1) | (r & 1);
            const int pos = atomicAdd(&lcur[st], 1);      // int LDS atomic
            payload[pos] = make_int2(((r & 63) << 17) | cols[e],
                                     __float_as_int(hk * vals[e]));
        }
    }
}

// x (f32) -> xh (bf16), vectorized: float4 in, ushort4 out
static __global__ __launch_bounds__(256) void convert_kernel(
    const float* __restrict__ x, ushort* __restrict__ xh, int n4)
{
    const int i = blockIdx.x * blockDim.x + threadIdx.x;
    if (i >= n4) return;
    const float4 v = ((const float4*)x)[i];
    ushort4 o;
    o.x = __bfloat16_as_ushort(__float2bfloat16(v.x));
    o.y = __bfloat16_as_ushort(__float2bfloat16(v.y));
    o.z = __bfloat16_as_ushort(__float2bfloat16(v.z));
    o.w = __bfloat16_as_ushort(__float2bfloat16(v.w));
    ((ushort4*)xh)[i] = o;
}

static __global__ __launch_bounds__(128) void spmv_bf16_kernel(
    const int*    __restrict__ ssBeg,
    const int2*   __restrict__ payload,
    const ushort* __restrict__ xh,
    float*        __restrict__ out,
    int N)
{
    __shared__ float acc[RPB * 64];            // 16KB
    const int b = blockIdx.x;
    for (int i = threadIdx.x; i < RPB * 64; i += 128) acc[i] = 0.f;
    __syncthreads();

    const int lane = threadIdx.x & 63;
    const int wv   = threadIdx.x >> 6;         // 0..1, owns rows r%2==wv
    const int s    = b * SUB + wv;
    int e        = ssBeg[s];
    const int be = ssBeg[s + 1];

    while (e + 16 <= be) {
        int2 pa[8], pb[8];
        float xa[8], xb[8];
        #pragma unroll
        for (int j = 0; j < 8; ++j) pa[j] = payload[e + j];
        #pragma unroll
        for (int j = 0; j < 8; ++j) pb[j] = payload[e + 8 + j];
        #pragma unroll
        for (int j = 0; j < 8; ++j)
            xa[j] = __bfloat162float(__ushort_as_bfloat16(
                        xh[(size_t)(pa[j].x & 0x1FFFF) * 64 + lane]));
        #pragma unroll
        for (int j = 0; j < 8; ++j)
            xb[j] = __bfloat162float(__ushort_as_bfloat16(
                        xh[(size_t)(pb[j].x & 0x1FFFF) * 64 + lane]));
        #pragma unroll
        for (int j = 0; j < 8; ++j)
            acc[(pa[j].x >> 17) * 64 + lane] += __int_as_float(pa[j].y) * xa[j];
        #pragma unroll
        for (int j = 0; j < 8; ++j)
            acc[(pb[j].x >> 17) * 64 + lane] += __int_as_float(pb[j].y) * xb[j];
        e += 16;
    }
    for (; e < be; ++e) {
        const int2 p = payload[e];
        const float xv = __bfloat162float(__ushort_as_bfloat16(
                             xh[(size_t)(p.x & 0x1FFFF) * 64 + lane]));
        acc[(p.x >> 17) * 64 + lane] += __int_as_float(p.y) * xv;
    }
    __syncthreads();

    const int base = b * RPB;
    const int nrow = min(RPB, N - base);
    for (int i = threadIdx.x; i < nrow * 64; i += 128)
        out[(size_t)base * 64 + i] = acc[i];
}

// f32-gather variant (round-5 proven) — used if ws can't hold the bf16 copy.
static __global__ __launch_bounds__(128) void spmv_f32_kernel(
    const int*  __restrict__ ssBeg,
    const int2* __restrict__ payload,
    const float* __restrict__ x,
    float*       __restrict__ out,
    int N)
{
    __shared__ float acc[RPB * 64];
    const int b = blockIdx.x;
    for (int i = threadIdx.x; i < RPB * 64; i += 128) acc[i] = 0.f;
    __syncthreads();

    const int lane = threadIdx.x & 63;
    const int wv   = threadIdx.x >> 6;
    const int s    = b * SUB + wv;
    int e        = ssBeg[s];
    const int be = ssBeg[s + 1];

    while (e + 16 <= be) {
        int2 pa[8], pb[8];
        float xa[8], xb[8];
        #pragma unroll
        for (int j = 0; j < 8; ++j) pa[j] = payload[e + j];
        #pragma unroll
        for (int j = 0; j < 8; ++j) pb[j] = payload[e + 8 + j];
        #pragma unroll
        for (int j = 0; j < 8; ++j)
            xa[j] = x[(size_t)(pa[j].x & 0x1FFFF) * 64 + lane];
        #pragma unroll
        for (int j = 0; j < 8; ++j)
            xb[j] = x[(size_t)(pb[j].x & 0x1FFFF) * 64 + lane];
        #pragma unroll
        for (int j = 0; j < 8; ++j)
            acc[(pa[j].x >> 17) * 64 + lane] += __int_as_float(pa[j].y) * xa[j];
        #pragma unroll
        for (int j = 0; j < 8; ++j)
            acc[(pb[j].x >> 17) * 64 + lane] += __int_as_float(pb[j].y) * xb[j];
        e += 16;
    }
    for (; e < be; ++e) {
        const int2 p = payload[e];
        acc[(p.x >> 17) * 64 + lane] +=
            __int_as_float(p.y) * x[(size_t)(p.x & 0x1FFFF) * 64 + lane];
    }
    __syncthreads();

    const int base = b * RPB;
    const int nrow = min(RPB, N - base);
    for (int i = threadIdx.x; i < nrow * 64; i += 128)
        out[(size_t)base * 64 + i] = acc[i];
}

// Round-1 fallback (atomic scatter) if ws is too small for binning at all.
static __global__ __launch_bounds__(256) void gtconv_scatter(
    const float* __restrict__ x, const float* __restrict__ h,
    const float* __restrict__ vals, const int* __restrict__ rows,
    const int* __restrict__ cols, float* __restrict__ out, int KE, int E)
{
    const int lane = threadIdx.x & 63;
    int wave = (blockIdx.x * blockDim.x + threadIdx.x) >> 6;
    const int nwaves = (gridDim.x * blockDim.x) >> 6;
    for (int e = wave; e < KE; e += nwaves) {
        float w = h[e / E] * vals[e];
        float xv = x[(size_t)cols[e] * 64 + lane];
        unsafeAtomicAdd(&out[(size_t)rows[e] * 64 + lane], xv * w);
    }
}

extern "C" void kernel_launch(void* const* d_in, const int* in_sizes, int n_in,
                              void* d_out, int out_size, void* d_ws, size_t ws_size,
                              hipStream_t stream) {
    const float* x    = (const float*)d_in[0];
    const float* h    = (const float*)d_in[1];
    const float* vals = (const float*)d_in[2];
    const int*   rows = (const int*)d_in[3];
    const int*   cols = (const int*)d_in[4];
    float* out = (float*)d_out;

    const int K  = in_sizes[1];
    const int KE = in_sizes[2];
    const int E  = KE / K;
    const int F  = 64;
    const int N  = in_sizes[0] / F;
    const int NB      = (N + RPB - 1) / RPB;       // 1563
    const int NSTREAM = NB * SUB;                  // 3126

    const size_t lds_need = (size_t)NSTREAM * 4;   // count/scatter LDS
    const size_t cnt_off  = 0;
    const size_t cnt_sz   = (size_t)NSTREAM * GWG * 4;
    const size_t ss_off   = cnt_off + cnt_sz;
    const size_t ss_sz    = (size_t)(NSTREAM + 1) * 4;
    const size_t pl_off   = (ss_off + ss_sz + 15) & ~(size_t)15;
    const size_t base_need = pl_off + (size_t)KE * 8;
    const size_t xh_off   = (base_need + 15) & ~(size_t)15;
    const size_t full_need = xh_off + (size_t)N * F * 2;

    if (ws_size < base_need || lds_need > 64 * 1024) {
        hipMemsetAsync(out, 0, (size_t)out_size * sizeof(float), stream);
        gtconv_scatter<<<8192, 256, 0, stream>>>(x, h, vals, rows, cols, out, KE, E);
        return;
    }

    char* ws = (char*)d_ws;
    int*    cnt     = (int*)(ws + cnt_off);
    int*    ssBeg   = (int*)(ws + ss_off);
    int2*   payload = (int2*)(ws + pl_off);
    ushort* xh      = (ushort*)(ws + xh_off);
    const bool use_bf16 = (ws_size >= full_need);

    const int chunk = (KE + GWG - 1) / GWG;

    if (use_bf16) {
        const int n4 = (N * F) / 4;
        convert_kernel<<<(n4 + 255) / 256, 256, 0, stream>>>(x, xh, n4);
    }
    count_kernel<<<GWG, 1024, lds_need, stream>>>(rows, cnt, KE, NSTREAM, chunk);
    scan1_kernel<<<NSTREAM, GWG, 0, stream>>>(cnt, ssBeg);
    scan2_kernel<<<1, 1024, 0, stream>>>(ssBeg, NSTREAM);
    const int total = NSTREAM * GWG;
    scan3_kernel<<<(total + 1023) / 1024, 1024, 0, stream>>>(cnt, ssBeg, total);
    scatter_kernel<<<GWG, 1024, lds_need, stream>>>(rows, cols, vals, h, cnt,
                                                    payload, KE, E, K, NSTREAM, chunk);
    if (use_bf16)
        spmv_bf16_kernel<<<NB, 128, 0, stream>>>(ssBeg, payload, xh, out, N);
    else
        spmv_f32_kernel<<<NB, 128, 0, stream>>>(ssBeg, payload, x, out, N);
}